// Round 9
// baseline (287.423 us; speedup 1.0000x reference)
//
#include <hip/hip_runtime.h>
#include <stdint.h>
#include <math.h>

#define D_IN   1024
#define NQKV   3072
#define NHEADS 16
#define DH     64
#define BATCH  4
#define SEQ    2048
#define MTOT   (BATCH*SEQ)   // 8192

typedef __bf16    bf16x8 __attribute__((ext_vector_type(8)));
typedef _Float16  f16x8  __attribute__((ext_vector_type(8)));
typedef float     f32x4  __attribute__((ext_vector_type(4)));
typedef float     f32x16 __attribute__((ext_vector_type(16)));

typedef __attribute__((address_space(3))) unsigned short       lds_us;
typedef __attribute__((address_space(1))) const unsigned short glb_us;

__device__ __forceinline__ unsigned short f2bf(float f) {
    union { float f; uint32_t u; } c; c.f = f;
    uint32_t u = c.u;
    uint32_t r = u + 0x7fffu + ((u >> 16) & 1u);  // RNE
    return (unsigned short)(r >> 16);
}
__device__ __forceinline__ uint32_t pkh(float a, float b) {
    auto h = __builtin_amdgcn_cvt_pkrtz(a, b);   // __fp16 ext_vector(2): low=a, high=b
    uint32_t u;
    __builtin_memcpy(&u, &h, 4);
    return u;
}

// ---------------- stage 0a: x fp32 -> bf16 ----------------
__global__ void k_convert_x(const float* __restrict__ x, unsigned short* __restrict__ xb) {
    int i = blockIdx.x * 256 + threadIdx.x;
    float4 v = ((const float4*)x)[i];
    ushort4 o;
    o.x = f2bf(v.x); o.y = f2bf(v.y); o.z = f2bf(v.z); o.w = f2bf(v.w);
    ((ushort4*)xb)[i] = o;
}

// ---------------- stage 0b: W fp32 [K][N] -> Wt bf16 [N][K] ----------------
__global__ void k_convert_wt(const float* __restrict__ W, unsigned short* __restrict__ Wt) {
    __shared__ float tile[32][33];
    int tx = threadIdx.x, ty = threadIdx.y;
    int n0 = blockIdx.x * 32, k0 = blockIdx.y * 32;
    #pragma unroll
    for (int i = 0; i < 4; ++i) {
        int k = k0 + ty + i*8;
        tile[ty + i*8][tx] = W[(size_t)k * NQKV + n0 + tx];
    }
    __syncthreads();
    #pragma unroll
    for (int i = 0; i < 4; ++i) {
        int n = n0 + ty + i*8;
        Wt[(size_t)n * D_IN + k0 + tx] = f2bf(tile[tx][ty + i*8]);
    }
}

// ---------------- stage 1: QKV GEMM with FRAGMENT-SCATTER epilogue ----------------
// (unchanged from R8 — verified passing) Writes Qbuf/Kfrag/Vfrag in the exact
// per-lane fragment order k_attn consumes; every k_attn in-loop load is a fully
// coalesced 1KB wave-read. Elem->key placements identical to the R6-verified math.
__global__ __launch_bounds__(256) void k_gemm_qkv(
    const unsigned short* __restrict__ A,   // [8192][1024] bf16
    const unsigned short* __restrict__ Bt,  // [3072][1024] bf16
    const float* __restrict__ bias,         // [3072]
    unsigned short* __restrict__ Qb,        // [8192][1024] bf16
    unsigned short* __restrict__ Kf,        // fragment layout, 8M shorts
    unsigned short* __restrict__ Vf)        // fragment layout, 8M shorts (f16)
{
    __shared__ __align__(16) unsigned short As[128*32];
    __shared__ __align__(16) unsigned short Bs[128*32];
    const int t = threadIdx.x;
    const int wave = t >> 6, lane = t & 63, quad = lane >> 4, l15 = lane & 15;
    const int wm = wave >> 1, wn = wave & 1;
    const int m0 = blockIdx.y * 128, n0 = blockIdx.x * 128;
    const int crow = lane >> 2;          // row within 16-row chunk
    const int ccol = (lane & 3) << 3;    // short col within row

    f32x4 acc[4][4] = {};
    lds_us* As3 = (lds_us*)As;
    lds_us* Bs3 = (lds_us*)Bs;

    for (int k0 = 0; k0 < D_IN; k0 += 32) {
        #pragma unroll
        for (int j = 0; j < 2; ++j) {
            int chunk = wave*2 + j;
            const unsigned short* ga = A  + (size_t)(m0 + chunk*16 + crow)*D_IN + k0 + ccol;
            const unsigned short* gb = Bt + (size_t)(n0 + chunk*16 + crow)*D_IN + k0 + ccol;
            __builtin_amdgcn_global_load_lds((glb_us*)ga, As3 + chunk*512, 16, 0, 0);
            __builtin_amdgcn_global_load_lds((glb_us*)gb, Bs3 + chunk*512, 16, 0, 0);
        }
        __syncthreads();
        bf16x8 a[4], b[4];
        #pragma unroll
        for (int tm = 0; tm < 4; ++tm)
            a[tm] = *(const bf16x8*)(&As[(wm*64 + tm*16 + l15)*32 + quad*8]);
        #pragma unroll
        for (int tn = 0; tn < 4; ++tn)
            b[tn] = *(const bf16x8*)(&Bs[(wn*64 + tn*16 + l15)*32 + quad*8]);
        #pragma unroll
        for (int tm = 0; tm < 4; ++tm)
            #pragma unroll
            for (int tn = 0; tn < 4; ++tn)
                acc[tm][tn] = __builtin_amdgcn_mfma_f32_16x16x32_bf16(a[tm], b[tn], acc[tm][tn], 0, 0, 0);
        __syncthreads();
    }
    const float qs = 0.125f * 1.44269504089f;
    #pragma unroll
    for (int tn = 0; tn < 4; ++tn) {
        const int col0 = n0 + wn*64 + tn*16;     // lane-uniform
        const int h   = col0 / 192;
        const int r0  = col0 - h*192;            // 0..191, run of 16 stays in one kind
        const float bv = bias[col0 + l15];
        if (r0 < 64) {
            // ---- Q: Qbuf[row][h*64 + dk], scaled ----
            const int dk = r0 + l15;
            #pragma unroll
            for (int tm = 0; tm < 4; ++tm)
                #pragma unroll
                for (int r = 0; r < 4; ++r) {
                    int row = m0 + wm*64 + tm*16 + quad*4 + r;
                    Qb[(size_t)row*1024 + h*64 + dk] = f2bf((acc[tm][tn][r] + bv) * qs);
                }
        } else if (r0 < 128) {
            // ---- K fragment scatter ----
            const int dk = r0 - 64 + l15;
            const int st = dk >> 4, hi2 = (dk >> 3) & 1, j = dk & 7;
            #pragma unroll
            for (int tm = 0; tm < 4; ++tm)
                #pragma unroll
                for (int r = 0; r < 4; ++r) {
                    int row = m0 + wm*64 + tm*16 + quad*4 + r;
                    int bh = ((row >> 11) << 4) + h;
                    int chunk = (row >> 5) & 63, l31r = row & 31;
                    Kf[((size_t)(bh*64 + chunk)*4 + st)*512 + (hi2*32 + l31r)*8 + j] =
                        f2bf(acc[tm][tn][r] + bv);
                }
        } else {
            // ---- V fragment scatter (f16) ----
            const int d = r0 - 128 + l15;
            const int dt = d >> 5, l31d = d & 31;
            #pragma unroll
            for (int tm = 0; tm < 4; ++tm)
                #pragma unroll
                for (int r = 0; r < 4; ++r) {
                    int row = m0 + wm*64 + tm*16 + quad*4 + r;
                    int bh = ((row >> 11) << 4) + h;
                    int chunk = (row >> 5) & 63;
                    int kc = row & 31, kh = kc >> 4, rem = kc & 15;
                    int hi2 = (rem >> 2) & 1;
                    int j = (rem & 3) | (((rem >> 3) & 1) << 2);
                    _Float16 hv = (_Float16)(acc[tm][tn][r] + bv);
                    Vf[(((size_t)(bh*64 + chunk)*2 + dt)*2 + kh)*512 + (hi2*32 + l31d)*8 + j] =
                        *(unsigned short*)&hv;
                }
        }
    }
}

// ---------------- stage 2: flash attention, ZERO-LDS, 32x32 MFMA, coalesced frags ----------------
// R9: cut the intra-wave critical path (R8 post-mortem: period ~1160 cyc/wave-iter vs
// ~500 cyc of pipe demand at ~2 waves/SIMD; the serial QK-chain -> full-exp -> PV
// path dominated). Two reorderings, math/layout identical to R8 (verified passing):
//  1. QK split into TWO independent 2-chains (sa, sb) issued interleaved, combined
//     with 16 v_add_f32: dependent-MFMA chain 4 -> 2 (~-128 cyc latency, +32 VALU).
//  2. exp/pack of S[0..7] -> pf0 -> issue pf0's 2 PV MFMAs -> exp/pack S[8..15]
//     (trans pipe overlaps pf0 PV on the matrix pipe) -> pf1's 2 PV MFMAs.
// Everything else unchanged: per-iter 4 kf + 4 vf coalesced 1KB loads, no LDS,
// no barriers, K/V single-buffered + reloaded right after last use.
__global__ __launch_bounds__(256) void k_attn(
    const unsigned short* __restrict__ Qb,  // [8192][1024] bf16 (pre-scaled)
    const unsigned short* __restrict__ Kf,  // fragment layout bf16
    const unsigned short* __restrict__ Vf,  // fragment layout f16
    float* __restrict__ out)
{
    const int t = threadIdx.x;
    const int wave = t >> 6, lane = t & 63;
    const int l31 = lane & 31, hi = lane >> 5;
    const int bh = blockIdx.x, b = bh >> 4, h = bh & 15;
    const int q0 = blockIdx.y * 128 + wave * 32;

    const unsigned short* qrow = Qb + (size_t)(b*SEQ + q0 + l31)*1024 + h*64;
    const unsigned short* kfb  = Kf + (size_t)bh * 64*4*512 + lane*8;       // + (chunk*4+st)*512
    const unsigned short* vfb  = Vf + (size_t)bh * 64*2*2*512 + lane*8;     // + ((chunk*2+dt)*2+kh)*512

    // Q B-frags: n = q = q0+l31, elem j of frag st at global dk = st*16 + hi*8 + j.
    bf16x8 qf[4];
    #pragma unroll
    for (int st = 0; st < 4; ++st)
        qf[st] = *(const bf16x8*)(qrow + st*16 + hi*8);

    // K A-frags (same elem->dk placement as qf -> QK correct under any k_inst mapping)
    bf16x8 kf[4];
    #pragma unroll
    for (int st = 0; st < 4; ++st)
        kf[st] = *(const bf16x8*)(kfb + st*512);
    // V A-frags (elem->key placement matches the packed P word order)
    f16x8 vf[2][2];
    #pragma unroll
    for (int dt = 0; dt < 2; ++dt)
        #pragma unroll
        for (int kh = 0; kh < 2; ++kh)
            vf[dt][kh] = *(const f16x8*)(vfb + (dt*2 + kh)*512);

    f32x16 o0 = {}, o1 = {};   // O^T tiles: d = dt*32 + (reg&3)+8*(reg>>2)+4*hi, q = l31
    float lp = 0.f;

    for (int it = 0; it < 64; ++it) {
        // QK: S^T[key][q], key = (reg&3)+8*(reg>>2)+4*hi (+it*32), q = q0+l31
        // two independent accumulation chains, interleaved issue
        f32x16 sa = {}, sb = {};
        __builtin_amdgcn_s_setprio(1);
        sa = __builtin_amdgcn_mfma_f32_32x32x16_bf16(kf[0], qf[0], sa, 0, 0, 0);
        sb = __builtin_amdgcn_mfma_f32_32x32x16_bf16(kf[2], qf[2], sb, 0, 0, 0);
        sa = __builtin_amdgcn_mfma_f32_32x32x16_bf16(kf[1], qf[1], sa, 0, 0, 0);
        sb = __builtin_amdgcn_mfma_f32_32x32x16_bf16(kf[3], qf[3], sb, 0, 0, 0);
        __builtin_amdgcn_s_setprio(0);
        // kf consumed -> reload next chunk (exp+PV hides the latency)
        if (it < 63) {
            const unsigned short* kn = kfb + (size_t)(it+1)*4*512;
            #pragma unroll
            for (int st = 0; st < 4; ++st)
                kf[st] = *(const bf16x8*)(kn + st*512);
        }
        // combine chains (only the half being consumed next is on the critical path)
        // exp2 (scale pre-folded into Q), l-partials, pack key-pairs to f16.
        // w0..w3 cover keys {4hi+0,1},{4hi+2,3},{8+4hi+0,1},{8+4hi+2,3}; w4..w7 same +16.
        uint32_t w0, w1, w2, w3;
        {
            float p0, p1, p2, p3;
            p0 = exp2f(sa[0]+sb[0]);  p1 = exp2f(sa[1]+sb[1]);
            p2 = exp2f(sa[2]+sb[2]);  p3 = exp2f(sa[3]+sb[3]);
            lp += (p0+p1)+(p2+p3); w0 = pkh(p0,p1); w1 = pkh(p2,p3);
            p0 = exp2f(sa[4]+sb[4]);  p1 = exp2f(sa[5]+sb[5]);
            p2 = exp2f(sa[6]+sb[6]);  p3 = exp2f(sa[7]+sb[7]);
            lp += (p0+p1)+(p2+p3); w2 = pkh(p0,p1); w3 = pkh(p2,p3);
        }
        f16x8 pf0;
        {
            union { uint32_t u[4]; f16x8 v; } cc;
            cc.u[0] = w0; cc.u[1] = w1; cc.u[2] = w2; cc.u[3] = w3; pf0 = cc.v;
        }
        // PV pair 0 issues while the second half's exp runs on the trans pipe
        __builtin_amdgcn_s_setprio(1);
        o0 = __builtin_amdgcn_mfma_f32_32x32x16_f16(vf[0][0], pf0, o0, 0, 0, 0);
        o1 = __builtin_amdgcn_mfma_f32_32x32x16_f16(vf[1][0], pf0, o1, 0, 0, 0);
        __builtin_amdgcn_s_setprio(0);
        uint32_t w4, w5, w6, w7;
        {
            float p0, p1, p2, p3;
            p0 = exp2f(sa[8]+sb[8]);   p1 = exp2f(sa[9]+sb[9]);
            p2 = exp2f(sa[10]+sb[10]); p3 = exp2f(sa[11]+sb[11]);
            lp += (p0+p1)+(p2+p3); w4 = pkh(p0,p1); w5 = pkh(p2,p3);
            p0 = exp2f(sa[12]+sb[12]); p1 = exp2f(sa[13]+sb[13]);
            p2 = exp2f(sa[14]+sb[14]); p3 = exp2f(sa[15]+sb[15]);
            lp += (p0+p1)+(p2+p3); w6 = pkh(p0,p1); w7 = pkh(p2,p3);
        }
        f16x8 pf1;
        {
            union { uint32_t u[4]; f16x8 v; } cc;
            cc.u[0] = w4; cc.u[1] = w5; cc.u[2] = w6; cc.u[3] = w7; pf1 = cc.v;
        }
        __builtin_amdgcn_s_setprio(1);
        o0 = __builtin_amdgcn_mfma_f32_32x32x16_f16(vf[0][1], pf1, o0, 0, 0, 0);
        o1 = __builtin_amdgcn_mfma_f32_32x32x16_f16(vf[1][1], pf1, o1, 0, 0, 0);
        __builtin_amdgcn_s_setprio(0);
        // vf consumed -> reload next chunk (next QK hides the latency)
        if (it < 63) {
            const unsigned short* vn = vfb + (size_t)(it+1)*4*512;
            #pragma unroll
            for (int dt = 0; dt < 2; ++dt)
                #pragma unroll
                for (int kh = 0; kh < 2; ++kh)
                    vf[dt][kh] = *(const f16x8*)(vn + (dt*2 + kh)*512);
        }
    }

    // l: the two half-lanes of each q hold disjoint key sets
    float lt = lp + __shfl_xor(lp, 32);
    float rl = 1.0f / lt;

    // out[b, q, h*64 + d]; o0[4g+c] is at d = 8g + 4hi + c (c=0..3), o1 at d+32
    float* outb = out + (size_t)(b*SEQ + q0 + l31)*(NHEADS*DH) + h*DH + 4*hi;
    #pragma unroll
    for (int g = 0; g < 4; ++g) {
        float4 v0 = make_float4(o0[4*g]*rl, o0[4*g+1]*rl, o0[4*g+2]*rl, o0[4*g+3]*rl);
        float4 v1 = make_float4(o1[4*g]*rl, o1[4*g+1]*rl, o1[4*g+2]*rl, o1[4*g+3]*rl);
        *(float4*)(outb + 8*g)      = v0;
        *(float4*)(outb + 32 + 8*g) = v1;
    }
}

extern "C" void kernel_launch(void* const* d_in, const int* in_sizes, int n_in,
                              void* d_out, int out_size, void* d_ws, size_t ws_size,
                              hipStream_t stream) {
    const float* x    = (const float*)d_in[0];
    const float* W    = (const float*)d_in[1];
    const float* bias = (const float*)d_in[2];
    float* out = (float*)d_out;

    // workspace: 73.4 MB total
    unsigned short* xb = (unsigned short*)d_ws;                  // 16 MB
    unsigned short* Wt = xb + (size_t)MTOT * D_IN;               // 6 MB
    unsigned short* Qb = Wt + (size_t)NQKV * D_IN;               // 16 MB
    unsigned short* Kf = Qb + (size_t)MTOT * D_IN;               // 16 MB
    unsigned short* Vf = Kf + (size_t)MTOT * D_IN;               // 16 MB

    hipLaunchKernelGGL(k_convert_x,  dim3(MTOT*D_IN/4/256), dim3(256),    0, stream, x, xb);
    hipLaunchKernelGGL(k_convert_wt, dim3(NQKV/32, D_IN/32), dim3(32, 8), 0, stream, W, Wt);
    hipLaunchKernelGGL(k_gemm_qkv,   dim3(NQKV/128, MTOT/128), dim3(256), 0, stream, xb, Wt, bias, Qb, Kf, Vf);
    hipLaunchKernelGGL(k_attn,       dim3(BATCH*NHEADS, SEQ/128), dim3(256), 0, stream, Qb, Kf, Vf, out);
}

// Round 10
// 272.759 us; speedup vs baseline: 1.0538x; 1.0538x over previous
//
#include <hip/hip_runtime.h>
#include <stdint.h>
#include <math.h>

#define D_IN   1024
#define NQKV   3072
#define NHEADS 16
#define DH     64
#define BATCH  4
#define SEQ    2048
#define MTOT   (BATCH*SEQ)   // 8192

typedef __bf16    bf16x8 __attribute__((ext_vector_type(8)));
typedef _Float16  f16x8  __attribute__((ext_vector_type(8)));
typedef float     f32x4  __attribute__((ext_vector_type(4)));
typedef float     f32x16 __attribute__((ext_vector_type(16)));

typedef __attribute__((address_space(3))) unsigned short       lds_us;
typedef __attribute__((address_space(1))) const unsigned short glb_us;

__device__ __forceinline__ unsigned short f2bf(float f) {
    union { float f; uint32_t u; } c; c.f = f;
    uint32_t u = c.u;
    uint32_t r = u + 0x7fffu + ((u >> 16) & 1u);  // RNE
    return (unsigned short)(r >> 16);
}
__device__ __forceinline__ uint32_t pkh(float a, float b) {
    auto h = __builtin_amdgcn_cvt_pkrtz(a, b);   // __fp16 ext_vector(2): low=a, high=b
    uint32_t u;
    __builtin_memcpy(&u, &h, 4);
    return u;
}

// ---------------- stage 0a: x fp32 -> bf16 ----------------
__global__ void k_convert_x(const float* __restrict__ x, unsigned short* __restrict__ xb) {
    int i = blockIdx.x * 256 + threadIdx.x;
    float4 v = ((const float4*)x)[i];
    ushort4 o;
    o.x = f2bf(v.x); o.y = f2bf(v.y); o.z = f2bf(v.z); o.w = f2bf(v.w);
    ((ushort4*)xb)[i] = o;
}

// ---------------- stage 0b: W fp32 [K][N] -> Wt bf16 [N][K] ----------------
__global__ void k_convert_wt(const float* __restrict__ W, unsigned short* __restrict__ Wt) {
    __shared__ float tile[32][33];
    int tx = threadIdx.x, ty = threadIdx.y;
    int n0 = blockIdx.x * 32, k0 = blockIdx.y * 32;
    #pragma unroll
    for (int i = 0; i < 4; ++i) {
        int k = k0 + ty + i*8;
        tile[ty + i*8][tx] = W[(size_t)k * NQKV + n0 + tx];
    }
    __syncthreads();
    #pragma unroll
    for (int i = 0; i < 4; ++i) {
        int n = n0 + ty + i*8;
        Wt[(size_t)n * D_IN + k0 + tx] = f2bf(tile[tx][ty + i*8]);
    }
}

// ---------------- stage 1: QKV GEMM with FRAGMENT-SCATTER epilogue ----------------
// (unchanged from R8 — verified passing) Writes Qbuf/Kfrag/Vfrag in the exact
// per-lane fragment order k_attn consumes; every k_attn in-loop load is a fully
// coalesced 1KB wave-read. Elem->key placements identical to the R6-verified math.
__global__ __launch_bounds__(256) void k_gemm_qkv(
    const unsigned short* __restrict__ A,   // [8192][1024] bf16
    const unsigned short* __restrict__ Bt,  // [3072][1024] bf16
    const float* __restrict__ bias,         // [3072]
    unsigned short* __restrict__ Qb,        // [8192][1024] bf16
    unsigned short* __restrict__ Kf,        // fragment layout, 8M shorts
    unsigned short* __restrict__ Vf)        // fragment layout, 8M shorts (f16)
{
    __shared__ __align__(16) unsigned short As[128*32];
    __shared__ __align__(16) unsigned short Bs[128*32];
    const int t = threadIdx.x;
    const int wave = t >> 6, lane = t & 63, quad = lane >> 4, l15 = lane & 15;
    const int wm = wave >> 1, wn = wave & 1;
    const int m0 = blockIdx.y * 128, n0 = blockIdx.x * 128;
    const int crow = lane >> 2;          // row within 16-row chunk
    const int ccol = (lane & 3) << 3;    // short col within row

    f32x4 acc[4][4] = {};
    lds_us* As3 = (lds_us*)As;
    lds_us* Bs3 = (lds_us*)Bs;

    for (int k0 = 0; k0 < D_IN; k0 += 32) {
        #pragma unroll
        for (int j = 0; j < 2; ++j) {
            int chunk = wave*2 + j;
            const unsigned short* ga = A  + (size_t)(m0 + chunk*16 + crow)*D_IN + k0 + ccol;
            const unsigned short* gb = Bt + (size_t)(n0 + chunk*16 + crow)*D_IN + k0 + ccol;
            __builtin_amdgcn_global_load_lds((glb_us*)ga, As3 + chunk*512, 16, 0, 0);
            __builtin_amdgcn_global_load_lds((glb_us*)gb, Bs3 + chunk*512, 16, 0, 0);
        }
        __syncthreads();
        bf16x8 a[4], b[4];
        #pragma unroll
        for (int tm = 0; tm < 4; ++tm)
            a[tm] = *(const bf16x8*)(&As[(wm*64 + tm*16 + l15)*32 + quad*8]);
        #pragma unroll
        for (int tn = 0; tn < 4; ++tn)
            b[tn] = *(const bf16x8*)(&Bs[(wn*64 + tn*16 + l15)*32 + quad*8]);
        #pragma unroll
        for (int tm = 0; tm < 4; ++tm)
            #pragma unroll
            for (int tn = 0; tn < 4; ++tn)
                acc[tm][tn] = __builtin_amdgcn_mfma_f32_16x16x32_bf16(a[tm], b[tn], acc[tm][tn], 0, 0, 0);
        __syncthreads();
    }
    const float qs = 0.125f * 1.44269504089f;
    #pragma unroll
    for (int tn = 0; tn < 4; ++tn) {
        const int col0 = n0 + wn*64 + tn*16;     // lane-uniform
        const int h   = col0 / 192;
        const int r0  = col0 - h*192;            // 0..191, run of 16 stays in one kind
        const float bv = bias[col0 + l15];
        if (r0 < 64) {
            // ---- Q: Qbuf[row][h*64 + dk], scaled ----
            const int dk = r0 + l15;
            #pragma unroll
            for (int tm = 0; tm < 4; ++tm)
                #pragma unroll
                for (int r = 0; r < 4; ++r) {
                    int row = m0 + wm*64 + tm*16 + quad*4 + r;
                    Qb[(size_t)row*1024 + h*64 + dk] = f2bf((acc[tm][tn][r] + bv) * qs);
                }
        } else if (r0 < 128) {
            // ---- K fragment scatter ----
            const int dk = r0 - 64 + l15;
            const int st = dk >> 4, hi2 = (dk >> 3) & 1, j = dk & 7;
            #pragma unroll
            for (int tm = 0; tm < 4; ++tm)
                #pragma unroll
                for (int r = 0; r < 4; ++r) {
                    int row = m0 + wm*64 + tm*16 + quad*4 + r;
                    int bh = ((row >> 11) << 4) + h;
                    int chunk = (row >> 5) & 63, l31r = row & 31;
                    Kf[((size_t)(bh*64 + chunk)*4 + st)*512 + (hi2*32 + l31r)*8 + j] =
                        f2bf(acc[tm][tn][r] + bv);
                }
        } else {
            // ---- V fragment scatter (f16) ----
            const int d = r0 - 128 + l15;
            const int dt = d >> 5, l31d = d & 31;
            #pragma unroll
            for (int tm = 0; tm < 4; ++tm)
                #pragma unroll
                for (int r = 0; r < 4; ++r) {
                    int row = m0 + wm*64 + tm*16 + quad*4 + r;
                    int bh = ((row >> 11) << 4) + h;
                    int chunk = (row >> 5) & 63;
                    int kc = row & 31, kh = kc >> 4, rem = kc & 15;
                    int hi2 = (rem >> 2) & 1;
                    int j = (rem & 3) | (((rem >> 3) & 1) << 2);
                    _Float16 hv = (_Float16)(acc[tm][tn][r] + bv);
                    Vf[(((size_t)(bh*64 + chunk)*2 + dt)*2 + kh)*512 + (hi2*32 + l31d)*8 + j] =
                        *(unsigned short*)&hv;
                }
        }
    }
}

// ---------------- stage 2: flash attention, ZERO-LDS, 64 q-rows per wave ----------------
// R10: double q per wave (32 -> 64 rows, two B-fragments qfa/qfb), grid y 16 -> 8.
// Rationale (R8/R9 post-mortem): R9's chain-split regressed (reverted to R8's
// schedule per half); R8's remaining limiter audit showed in-loop L2 read traffic
// = 2.1 GB = ~17 TB/s (~50% of the L2 ceiling) with K/V loads 100% wave-redundant
// within a block (kfb/vfb have no wave dependence). Doubling q per K/V load:
//  * halves L2 traffic (1.05 GB, ~8.5 TB/s),
//  * doubles per-iter independent MFMA work (sa/sb are REAL independent outputs —
//    two dep-chains, no combine adds, unlike R9),
//  * b-half exp/pack runs on the trans pipe while a-half PV holds the matrix pipe.
// 512 blocks = 2/CU = 8 waves/CU, all resident in one batch (same residency as R8).
// Regs ~84 arch + 96 acc (oa/ob 64 + sa/sb 32) ~ 180 -> 2 waves/SIMD, no spill.
__global__ __launch_bounds__(256) void k_attn(
    const unsigned short* __restrict__ Qb,  // [8192][1024] bf16 (pre-scaled)
    const unsigned short* __restrict__ Kf,  // fragment layout bf16
    const unsigned short* __restrict__ Vf,  // fragment layout f16
    float* __restrict__ out)
{
    const int t = threadIdx.x;
    const int wave = t >> 6, lane = t & 63;
    const int l31 = lane & 31, hi = lane >> 5;
    const int bh = blockIdx.x, b = bh >> 4, h = bh & 15;
    const int q0 = blockIdx.y * 256 + wave * 64;   // wave owns q0..q0+63

    const unsigned short* qrowa = Qb + (size_t)(b*SEQ + q0 + l31)*1024 + h*64;
    const unsigned short* qrowb = qrowa + (size_t)32*1024;
    const unsigned short* kfb  = Kf + (size_t)bh * 64*4*512 + lane*8;       // + (chunk*4+st)*512
    const unsigned short* vfb  = Vf + (size_t)bh * 64*2*2*512 + lane*8;     // + ((chunk*2+dt)*2+kh)*512

    // Q B-frags: n = q, elem j of frag st at global dk = st*16 + hi*8 + j.
    bf16x8 qfa[4], qfb4[4];
    #pragma unroll
    for (int st = 0; st < 4; ++st) {
        qfa[st]  = *(const bf16x8*)(qrowa + st*16 + hi*8);
        qfb4[st] = *(const bf16x8*)(qrowb + st*16 + hi*8);
    }

    // K A-frags (same elem->dk placement as qf -> QK correct under any k_inst mapping)
    bf16x8 kf[4];
    #pragma unroll
    for (int st = 0; st < 4; ++st)
        kf[st] = *(const bf16x8*)(kfb + st*512);
    // V A-frags (elem->key placement matches the packed P word order)
    f16x8 vf[2][2];
    #pragma unroll
    for (int dt = 0; dt < 2; ++dt)
        #pragma unroll
        for (int kh = 0; kh < 2; ++kh)
            vf[dt][kh] = *(const f16x8*)(vfb + (dt*2 + kh)*512);

    f32x16 oa0 = {}, oa1 = {}, ob0 = {}, ob1 = {};  // O^T: d = dt*32+(r&3)+8*(r>>2)+4*hi
    float lpa = 0.f, lpb = 0.f;

    for (int it = 0; it < 64; ++it) {
        // QK for both halves: two INDEPENDENT dep-chains, interleaved issue
        f32x16 sa = {}, sb = {};
        __builtin_amdgcn_s_setprio(1);
        sa = __builtin_amdgcn_mfma_f32_32x32x16_bf16(kf[0], qfa[0],  sa, 0, 0, 0);
        sb = __builtin_amdgcn_mfma_f32_32x32x16_bf16(kf[0], qfb4[0], sb, 0, 0, 0);
        sa = __builtin_amdgcn_mfma_f32_32x32x16_bf16(kf[1], qfa[1],  sa, 0, 0, 0);
        sb = __builtin_amdgcn_mfma_f32_32x32x16_bf16(kf[1], qfb4[1], sb, 0, 0, 0);
        sa = __builtin_amdgcn_mfma_f32_32x32x16_bf16(kf[2], qfa[2],  sa, 0, 0, 0);
        sb = __builtin_amdgcn_mfma_f32_32x32x16_bf16(kf[2], qfb4[2], sb, 0, 0, 0);
        sa = __builtin_amdgcn_mfma_f32_32x32x16_bf16(kf[3], qfa[3],  sa, 0, 0, 0);
        sb = __builtin_amdgcn_mfma_f32_32x32x16_bf16(kf[3], qfb4[3], sb, 0, 0, 0);
        __builtin_amdgcn_s_setprio(0);
        // kf consumed by both halves -> reload next chunk (exp+PV hides the latency)
        if (it < 63) {
            const unsigned short* kn = kfb + (size_t)(it+1)*4*512;
            #pragma unroll
            for (int st = 0; st < 4; ++st)
                kf[st] = *(const bf16x8*)(kn + st*512);
        }
        // ---- half a: exp/pack (R8 schedule) then PV ----
        {
            uint32_t w0, w1, w2, w3, w4, w5, w6, w7;
            float p0, p1, p2, p3;
            p0 = exp2f(sa[0]);  p1 = exp2f(sa[1]);  p2 = exp2f(sa[2]);  p3 = exp2f(sa[3]);
            lpa += (p0+p1)+(p2+p3); w0 = pkh(p0,p1); w1 = pkh(p2,p3);
            p0 = exp2f(sa[4]);  p1 = exp2f(sa[5]);  p2 = exp2f(sa[6]);  p3 = exp2f(sa[7]);
            lpa += (p0+p1)+(p2+p3); w2 = pkh(p0,p1); w3 = pkh(p2,p3);
            p0 = exp2f(sa[8]);  p1 = exp2f(sa[9]);  p2 = exp2f(sa[10]); p3 = exp2f(sa[11]);
            lpa += (p0+p1)+(p2+p3); w4 = pkh(p0,p1); w5 = pkh(p2,p3);
            p0 = exp2f(sa[12]); p1 = exp2f(sa[13]); p2 = exp2f(sa[14]); p3 = exp2f(sa[15]);
            lpa += (p0+p1)+(p2+p3); w6 = pkh(p0,p1); w7 = pkh(p2,p3);
            f16x8 pf0, pf1;
            union { uint32_t u[4]; f16x8 v; } cc;
            cc.u[0] = w0; cc.u[1] = w1; cc.u[2] = w2; cc.u[3] = w3; pf0 = cc.v;
            cc.u[0] = w4; cc.u[1] = w5; cc.u[2] = w6; cc.u[3] = w7; pf1 = cc.v;
            __builtin_amdgcn_s_setprio(1);
            oa0 = __builtin_amdgcn_mfma_f32_32x32x16_f16(vf[0][0], pf0, oa0, 0, 0, 0);
            oa1 = __builtin_amdgcn_mfma_f32_32x32x16_f16(vf[1][0], pf0, oa1, 0, 0, 0);
            oa0 = __builtin_amdgcn_mfma_f32_32x32x16_f16(vf[0][1], pf1, oa0, 0, 0, 0);
            oa1 = __builtin_amdgcn_mfma_f32_32x32x16_f16(vf[1][1], pf1, oa1, 0, 0, 0);
            __builtin_amdgcn_s_setprio(0);
        }
        // ---- half b: exp/pack (trans pipe overlaps half-a PV) then PV ----
        {
            uint32_t w0, w1, w2, w3, w4, w5, w6, w7;
            float p0, p1, p2, p3;
            p0 = exp2f(sb[0]);  p1 = exp2f(sb[1]);  p2 = exp2f(sb[2]);  p3 = exp2f(sb[3]);
            lpb += (p0+p1)+(p2+p3); w0 = pkh(p0,p1); w1 = pkh(p2,p3);
            p0 = exp2f(sb[4]);  p1 = exp2f(sb[5]);  p2 = exp2f(sb[6]);  p3 = exp2f(sb[7]);
            lpb += (p0+p1)+(p2+p3); w2 = pkh(p0,p1); w3 = pkh(p2,p3);
            p0 = exp2f(sb[8]);  p1 = exp2f(sb[9]);  p2 = exp2f(sb[10]); p3 = exp2f(sb[11]);
            lpb += (p0+p1)+(p2+p3); w4 = pkh(p0,p1); w5 = pkh(p2,p3);
            p0 = exp2f(sb[12]); p1 = exp2f(sb[13]); p2 = exp2f(sb[14]); p3 = exp2f(sb[15]);
            lpb += (p0+p1)+(p2+p3); w6 = pkh(p0,p1); w7 = pkh(p2,p3);
            f16x8 pf0, pf1;
            union { uint32_t u[4]; f16x8 v; } cc;
            cc.u[0] = w0; cc.u[1] = w1; cc.u[2] = w2; cc.u[3] = w3; pf0 = cc.v;
            cc.u[0] = w4; cc.u[1] = w5; cc.u[2] = w6; cc.u[3] = w7; pf1 = cc.v;
            __builtin_amdgcn_s_setprio(1);
            ob0 = __builtin_amdgcn_mfma_f32_32x32x16_f16(vf[0][0], pf0, ob0, 0, 0, 0);
            ob1 = __builtin_amdgcn_mfma_f32_32x32x16_f16(vf[1][0], pf0, ob1, 0, 0, 0);
            ob0 = __builtin_amdgcn_mfma_f32_32x32x16_f16(vf[0][1], pf1, ob0, 0, 0, 0);
            ob1 = __builtin_amdgcn_mfma_f32_32x32x16_f16(vf[1][1], pf1, ob1, 0, 0, 0);
            __builtin_amdgcn_s_setprio(0);
        }
        // vf consumed by both halves -> reload next chunk (next QK hides the latency)
        if (it < 63) {
            const unsigned short* vn = vfb + (size_t)(it+1)*4*512;
            #pragma unroll
            for (int dt = 0; dt < 2; ++dt)
                #pragma unroll
                for (int kh = 0; kh < 2; ++kh)
                    vf[dt][kh] = *(const f16x8*)(vn + (dt*2 + kh)*512);
        }
    }

    // l: the two half-lanes of each q hold disjoint key sets
    float lta = lpa + __shfl_xor(lpa, 32);
    float ltb = lpb + __shfl_xor(lpb, 32);
    float rla = 1.0f / lta, rlb = 1.0f / ltb;

    // out[b, q, h*64 + d]; oX0[4g+c] at d = 8g + 4hi + c, oX1 at d+32
    float* outa = out + (size_t)(b*SEQ + q0 + l31)*(NHEADS*DH) + h*DH + 4*hi;
    float* outbp = outa + (size_t)32*(NHEADS*DH);
    #pragma unroll
    for (int g = 0; g < 4; ++g) {
        float4 v0 = make_float4(oa0[4*g]*rla, oa0[4*g+1]*rla, oa0[4*g+2]*rla, oa0[4*g+3]*rla);
        float4 v1 = make_float4(oa1[4*g]*rla, oa1[4*g+1]*rla, oa1[4*g+2]*rla, oa1[4*g+3]*rla);
        *(float4*)(outa + 8*g)      = v0;
        *(float4*)(outa + 32 + 8*g) = v1;
        float4 u0 = make_float4(ob0[4*g]*rlb, ob0[4*g+1]*rlb, ob0[4*g+2]*rlb, ob0[4*g+3]*rlb);
        float4 u1 = make_float4(ob1[4*g]*rlb, ob1[4*g+1]*rlb, ob1[4*g+2]*rlb, ob1[4*g+3]*rlb);
        *(float4*)(outbp + 8*g)      = u0;
        *(float4*)(outbp + 32 + 8*g) = u1;
    }
}

extern "C" void kernel_launch(void* const* d_in, const int* in_sizes, int n_in,
                              void* d_out, int out_size, void* d_ws, size_t ws_size,
                              hipStream_t stream) {
    const float* x    = (const float*)d_in[0];
    const float* W    = (const float*)d_in[1];
    const float* bias = (const float*)d_in[2];
    float* out = (float*)d_out;

    // workspace: 73.4 MB total
    unsigned short* xb = (unsigned short*)d_ws;                  // 16 MB
    unsigned short* Wt = xb + (size_t)MTOT * D_IN;               // 6 MB
    unsigned short* Qb = Wt + (size_t)NQKV * D_IN;               // 16 MB
    unsigned short* Kf = Qb + (size_t)MTOT * D_IN;               // 16 MB
    unsigned short* Vf = Kf + (size_t)MTOT * D_IN;               // 16 MB

    hipLaunchKernelGGL(k_convert_x,  dim3(MTOT*D_IN/4/256), dim3(256),    0, stream, x, xb);
    hipLaunchKernelGGL(k_convert_wt, dim3(NQKV/32, D_IN/32), dim3(32, 8), 0, stream, W, Wt);
    hipLaunchKernelGGL(k_gemm_qkv,   dim3(NQKV/128, MTOT/128), dim3(256), 0, stream, xb, Wt, bias, Qb, Kf, Vf);
    hipLaunchKernelGGL(k_attn,       dim3(BATCH*NHEADS, SEQ/256), dim3(256), 0, stream, Qb, Kf, Vf, out);
}

// Round 11
// 263.608 us; speedup vs baseline: 1.0903x; 1.0347x over previous
//
#include <hip/hip_runtime.h>
#include <stdint.h>
#include <math.h>

#define D_IN   1024
#define NQKV   3072
#define NHEADS 16
#define DH     64
#define BATCH  4
#define SEQ    2048
#define MTOT   (BATCH*SEQ)   // 8192

typedef __bf16    bf16x8 __attribute__((ext_vector_type(8)));
typedef _Float16  f16x8  __attribute__((ext_vector_type(8)));
typedef float     f32x4  __attribute__((ext_vector_type(4)));
typedef float     f32x16 __attribute__((ext_vector_type(16)));

typedef __attribute__((address_space(3))) unsigned short       lds_us;
typedef __attribute__((address_space(1))) const unsigned short glb_us;

__device__ __forceinline__ unsigned short f2bf(float f) {
    union { float f; uint32_t u; } c; c.f = f;
    uint32_t u = c.u;
    uint32_t r = u + 0x7fffu + ((u >> 16) & 1u);  // RNE
    return (unsigned short)(r >> 16);
}
__device__ __forceinline__ uint32_t pkh(float a, float b) {
    auto h = __builtin_amdgcn_cvt_pkrtz(a, b);   // __fp16 ext_vector(2): low=a, high=b
    uint32_t u;
    __builtin_memcpy(&u, &h, 4);
    return u;
}

// ---------------- stage 0a: x fp32 -> bf16 ----------------
__global__ void k_convert_x(const float* __restrict__ x, unsigned short* __restrict__ xb) {
    int i = blockIdx.x * 256 + threadIdx.x;
    float4 v = ((const float4*)x)[i];
    ushort4 o;
    o.x = f2bf(v.x); o.y = f2bf(v.y); o.z = f2bf(v.z); o.w = f2bf(v.w);
    ((ushort4*)xb)[i] = o;
}

// ---------------- stage 0b: W fp32 [K][N] -> Wt bf16 [N][K] ----------------
__global__ void k_convert_wt(const float* __restrict__ W, unsigned short* __restrict__ Wt) {
    __shared__ float tile[32][33];
    int tx = threadIdx.x, ty = threadIdx.y;
    int n0 = blockIdx.x * 32, k0 = blockIdx.y * 32;
    #pragma unroll
    for (int i = 0; i < 4; ++i) {
        int k = k0 + ty + i*8;
        tile[ty + i*8][tx] = W[(size_t)k * NQKV + n0 + tx];
    }
    __syncthreads();
    #pragma unroll
    for (int i = 0; i < 4; ++i) {
        int n = n0 + ty + i*8;
        Wt[(size_t)n * D_IN + k0 + tx] = f2bf(tile[tx][ty + i*8]);
    }
}

// ---------------- stage 1: QKV GEMM with FRAGMENT-SCATTER epilogue ----------------
// (unchanged from R8 — verified passing) Writes Qbuf/Kfrag/Vfrag in the exact
// per-lane fragment order k_attn consumes; every k_attn in-loop load is a fully
// coalesced 1KB wave-read. Elem->key placements identical to the R6-verified math.
__global__ __launch_bounds__(256) void k_gemm_qkv(
    const unsigned short* __restrict__ A,   // [8192][1024] bf16
    const unsigned short* __restrict__ Bt,  // [3072][1024] bf16
    const float* __restrict__ bias,         // [3072]
    unsigned short* __restrict__ Qb,        // [8192][1024] bf16
    unsigned short* __restrict__ Kf,        // fragment layout, 8M shorts
    unsigned short* __restrict__ Vf)        // fragment layout, 8M shorts (f16)
{
    __shared__ __align__(16) unsigned short As[128*32];
    __shared__ __align__(16) unsigned short Bs[128*32];
    const int t = threadIdx.x;
    const int wave = t >> 6, lane = t & 63, quad = lane >> 4, l15 = lane & 15;
    const int wm = wave >> 1, wn = wave & 1;
    const int m0 = blockIdx.y * 128, n0 = blockIdx.x * 128;
    const int crow = lane >> 2;          // row within 16-row chunk
    const int ccol = (lane & 3) << 3;    // short col within row

    f32x4 acc[4][4] = {};
    lds_us* As3 = (lds_us*)As;
    lds_us* Bs3 = (lds_us*)Bs;

    for (int k0 = 0; k0 < D_IN; k0 += 32) {
        #pragma unroll
        for (int j = 0; j < 2; ++j) {
            int chunk = wave*2 + j;
            const unsigned short* ga = A  + (size_t)(m0 + chunk*16 + crow)*D_IN + k0 + ccol;
            const unsigned short* gb = Bt + (size_t)(n0 + chunk*16 + crow)*D_IN + k0 + ccol;
            __builtin_amdgcn_global_load_lds((glb_us*)ga, As3 + chunk*512, 16, 0, 0);
            __builtin_amdgcn_global_load_lds((glb_us*)gb, Bs3 + chunk*512, 16, 0, 0);
        }
        __syncthreads();
        bf16x8 a[4], b[4];
        #pragma unroll
        for (int tm = 0; tm < 4; ++tm)
            a[tm] = *(const bf16x8*)(&As[(wm*64 + tm*16 + l15)*32 + quad*8]);
        #pragma unroll
        for (int tn = 0; tn < 4; ++tn)
            b[tn] = *(const bf16x8*)(&Bs[(wn*64 + tn*16 + l15)*32 + quad*8]);
        #pragma unroll
        for (int tm = 0; tm < 4; ++tm)
            #pragma unroll
            for (int tn = 0; tn < 4; ++tn)
                acc[tm][tn] = __builtin_amdgcn_mfma_f32_16x16x32_bf16(a[tm], b[tn], acc[tm][tn], 0, 0, 0);
        __syncthreads();
    }
    const float qs = 0.125f * 1.44269504089f;
    #pragma unroll
    for (int tn = 0; tn < 4; ++tn) {
        const int col0 = n0 + wn*64 + tn*16;     // lane-uniform
        const int h   = col0 / 192;
        const int r0  = col0 - h*192;            // 0..191, run of 16 stays in one kind
        const float bv = bias[col0 + l15];
        if (r0 < 64) {
            // ---- Q: Qbuf[row][h*64 + dk], scaled ----
            const int dk = r0 + l15;
            #pragma unroll
            for (int tm = 0; tm < 4; ++tm)
                #pragma unroll
                for (int r = 0; r < 4; ++r) {
                    int row = m0 + wm*64 + tm*16 + quad*4 + r;
                    Qb[(size_t)row*1024 + h*64 + dk] = f2bf((acc[tm][tn][r] + bv) * qs);
                }
        } else if (r0 < 128) {
            // ---- K fragment scatter ----
            const int dk = r0 - 64 + l15;
            const int st = dk >> 4, hi2 = (dk >> 3) & 1, j = dk & 7;
            #pragma unroll
            for (int tm = 0; tm < 4; ++tm)
                #pragma unroll
                for (int r = 0; r < 4; ++r) {
                    int row = m0 + wm*64 + tm*16 + quad*4 + r;
                    int bh = ((row >> 11) << 4) + h;
                    int chunk = (row >> 5) & 63, l31r = row & 31;
                    Kf[((size_t)(bh*64 + chunk)*4 + st)*512 + (hi2*32 + l31r)*8 + j] =
                        f2bf(acc[tm][tn][r] + bv);
                }
        } else {
            // ---- V fragment scatter (f16) ----
            const int d = r0 - 128 + l15;
            const int dt = d >> 5, l31d = d & 31;
            #pragma unroll
            for (int tm = 0; tm < 4; ++tm)
                #pragma unroll
                for (int r = 0; r < 4; ++r) {
                    int row = m0 + wm*64 + tm*16 + quad*4 + r;
                    int bh = ((row >> 11) << 4) + h;
                    int chunk = (row >> 5) & 63;
                    int kc = row & 31, kh = kc >> 4, rem = kc & 15;
                    int hi2 = (rem >> 2) & 1;
                    int j = (rem & 3) | (((rem >> 3) & 1) << 2);
                    _Float16 hv = (_Float16)(acc[tm][tn][r] + bv);
                    Vf[(((size_t)(bh*64 + chunk)*2 + dt)*2 + kh)*512 + (hi2*32 + l31d)*8 + j] =
                        *(unsigned short*)&hv;
                }
        }
    }
}

// ---------------- stage 2: flash attention, ZERO-LDS, 32x32 MFMA, coalesced frags ----------------
// R11: R8's exact kernel (124us, best) + __launch_bounds__(256, 3).
// R10 post-mortem: halving L2 traffic (64q/wave) left dur flat -> NOT memory-bound;
// per-wave stall-bound with only 2 waves/SIMD whose stall phases correlate (lockstep).
// The lever is stall OVERLAP: 3 waves/SIMD. R8's live set is ~143 regs (qf16+kf16+
// vf16+o32+s16+pf8+ptrs+misc), which FITS the 168-reg cap of min-waves=3 — unlike
// R1's 188-reg working set which spilled under the same cap. Watch WRITE_SIZE:
// ~33MB = clean; growth = spill = revert to plain R8.
__global__ __launch_bounds__(256, 3) void k_attn(
    const unsigned short* __restrict__ Qb,  // [8192][1024] bf16 (pre-scaled)
    const unsigned short* __restrict__ Kf,  // fragment layout bf16
    const unsigned short* __restrict__ Vf,  // fragment layout f16
    float* __restrict__ out)
{
    const int t = threadIdx.x;
    const int wave = t >> 6, lane = t & 63;
    const int l31 = lane & 31, hi = lane >> 5;
    const int bh = blockIdx.x, b = bh >> 4, h = bh & 15;
    const int q0 = blockIdx.y * 128 + wave * 32;

    const unsigned short* qrow = Qb + (size_t)(b*SEQ + q0 + l31)*1024 + h*64;
    const unsigned short* kfb  = Kf + (size_t)bh * 64*4*512 + lane*8;       // + (chunk*4+st)*512
    const unsigned short* vfb  = Vf + (size_t)bh * 64*2*2*512 + lane*8;     // + ((chunk*2+dt)*2+kh)*512

    // Q B-frags: n = q = q0+l31, elem j of frag st at global dk = st*16 + hi*8 + j.
    bf16x8 qf[4];
    #pragma unroll
    for (int st = 0; st < 4; ++st)
        qf[st] = *(const bf16x8*)(qrow + st*16 + hi*8);

    // K A-frags (same elem->dk placement as qf -> QK correct under any k_inst mapping)
    bf16x8 kf[4];
    #pragma unroll
    for (int st = 0; st < 4; ++st)
        kf[st] = *(const bf16x8*)(kfb + st*512);
    // V A-frags (elem->key placement matches the packed P word order)
    f16x8 vf[2][2];
    #pragma unroll
    for (int dt = 0; dt < 2; ++dt)
        #pragma unroll
        for (int kh = 0; kh < 2; ++kh)
            vf[dt][kh] = *(const f16x8*)(vfb + (dt*2 + kh)*512);

    f32x16 o0 = {}, o1 = {};   // O^T tiles: d = dt*32 + (reg&3)+8*(reg>>2)+4*hi, q = l31
    float lp = 0.f;

    for (int it = 0; it < 64; ++it) {
        // QK: S^T[key][q], key = (reg&3)+8*(reg>>2)+4*hi (+it*32), q = q0+l31
        f32x16 s = {};
        __builtin_amdgcn_s_setprio(1);
        #pragma unroll
        for (int st = 0; st < 4; ++st)
            s = __builtin_amdgcn_mfma_f32_32x32x16_bf16(kf[st], qf[st], s, 0, 0, 0);
        __builtin_amdgcn_s_setprio(0);
        // kf consumed -> reload next chunk (exp+PV hides the latency)
        if (it < 63) {
            const unsigned short* kn = kfb + (size_t)(it+1)*4*512;
            #pragma unroll
            for (int st = 0; st < 4; ++st)
                kf[st] = *(const bf16x8*)(kn + st*512);
        }
        // exp2 (scale pre-folded into Q), l-partials, pack key-pairs to f16.
        // w0..w3 cover keys {4hi+0,1},{4hi+2,3},{8+4hi+0,1},{8+4hi+2,3}; w4..w7 same +16.
        uint32_t w0, w1, w2, w3, w4, w5, w6, w7;
        {
            float p0, p1, p2, p3;
            p0 = exp2f(s[0]);  p1 = exp2f(s[1]);  p2 = exp2f(s[2]);  p3 = exp2f(s[3]);
            lp += (p0+p1)+(p2+p3); w0 = pkh(p0,p1); w1 = pkh(p2,p3);
            p0 = exp2f(s[4]);  p1 = exp2f(s[5]);  p2 = exp2f(s[6]);  p3 = exp2f(s[7]);
            lp += (p0+p1)+(p2+p3); w2 = pkh(p0,p1); w3 = pkh(p2,p3);
            p0 = exp2f(s[8]);  p1 = exp2f(s[9]);  p2 = exp2f(s[10]); p3 = exp2f(s[11]);
            lp += (p0+p1)+(p2+p3); w4 = pkh(p0,p1); w5 = pkh(p2,p3);
            p0 = exp2f(s[12]); p1 = exp2f(s[13]); p2 = exp2f(s[14]); p3 = exp2f(s[15]);
            lp += (p0+p1)+(p2+p3); w6 = pkh(p0,p1); w7 = pkh(p2,p3);
        }
        f16x8 pf0, pf1;
        {
            union { uint32_t u[4]; f16x8 v; } cc;
            cc.u[0] = w0; cc.u[1] = w1; cc.u[2] = w2; cc.u[3] = w3; pf0 = cc.v;
            cc.u[0] = w4; cc.u[1] = w5; cc.u[2] = w6; cc.u[3] = w7; pf1 = cc.v;
        }
        // PV: O^T += V^T · P^T  (A/B elem->key placements identical by construction)
        __builtin_amdgcn_s_setprio(1);
        o0 = __builtin_amdgcn_mfma_f32_32x32x16_f16(vf[0][0], pf0, o0, 0, 0, 0);
        o1 = __builtin_amdgcn_mfma_f32_32x32x16_f16(vf[1][0], pf0, o1, 0, 0, 0);
        o0 = __builtin_amdgcn_mfma_f32_32x32x16_f16(vf[0][1], pf1, o0, 0, 0, 0);
        o1 = __builtin_amdgcn_mfma_f32_32x32x16_f16(vf[1][1], pf1, o1, 0, 0, 0);
        __builtin_amdgcn_s_setprio(0);
        // vf consumed -> reload next chunk (next QK hides the latency)
        if (it < 63) {
            const unsigned short* vn = vfb + (size_t)(it+1)*4*512;
            #pragma unroll
            for (int dt = 0; dt < 2; ++dt)
                #pragma unroll
                for (int kh = 0; kh < 2; ++kh)
                    vf[dt][kh] = *(const f16x8*)(vn + (dt*2 + kh)*512);
        }
    }

    // l: the two half-lanes of each q hold disjoint key sets
    float lt = lp + __shfl_xor(lp, 32);
    float rl = 1.0f / lt;

    // out[b, q, h*64 + d]; o0[4g+c] is at d = 8g + 4hi + c (c=0..3), o1 at d+32
    float* outb = out + (size_t)(b*SEQ + q0 + l31)*(NHEADS*DH) + h*DH + 4*hi;
    #pragma unroll
    for (int g = 0; g < 4; ++g) {
        float4 v0 = make_float4(o0[4*g]*rl, o0[4*g+1]*rl, o0[4*g+2]*rl, o0[4*g+3]*rl);
        float4 v1 = make_float4(o1[4*g]*rl, o1[4*g+1]*rl, o1[4*g+2]*rl, o1[4*g+3]*rl);
        *(float4*)(outb + 8*g)      = v0;
        *(float4*)(outb + 32 + 8*g) = v1;
    }
}

extern "C" void kernel_launch(void* const* d_in, const int* in_sizes, int n_in,
                              void* d_out, int out_size, void* d_ws, size_t ws_size,
                              hipStream_t stream) {
    const float* x    = (const float*)d_in[0];
    const float* W    = (const float*)d_in[1];
    const float* bias = (const float*)d_in[2];
    float* out = (float*)d_out;

    // workspace: 73.4 MB total
    unsigned short* xb = (unsigned short*)d_ws;                  // 16 MB
    unsigned short* Wt = xb + (size_t)MTOT * D_IN;               // 6 MB
    unsigned short* Qb = Wt + (size_t)NQKV * D_IN;               // 16 MB
    unsigned short* Kf = Qb + (size_t)MTOT * D_IN;               // 16 MB
    unsigned short* Vf = Kf + (size_t)MTOT * D_IN;               // 16 MB

    hipLaunchKernelGGL(k_convert_x,  dim3(MTOT*D_IN/4/256), dim3(256),    0, stream, x, xb);
    hipLaunchKernelGGL(k_convert_wt, dim3(NQKV/32, D_IN/32), dim3(32, 8), 0, stream, W, Wt);
    hipLaunchKernelGGL(k_gemm_qkv,   dim3(NQKV/128, MTOT/128), dim3(256), 0, stream, xb, Wt, bias, Qb, Kf, Vf);
    hipLaunchKernelGGL(k_attn,       dim3(BATCH*NHEADS, SEQ/128), dim3(256), 0, stream, Qb, Kf, Vf, out);
}